// Round 17
// baseline (34.387 us; speedup 1.0000x reference)
//
#include <hip/hip_runtime.h>
#include <hip/hip_bf16.h>

#define BD 4
#define SD 2048
#define DD 512
#define VD 32000
#define NTOK (BD * SD)
#define EPS_L2 1e-12f
#define RPB 32                 // rows per block (8 waves x 4 rows each)
#define NBLK (VD / RPB)        // 1000
#define MAXTOK 32

// 16B vector with 4B alignment (stores land at out+1+...; dwordx4 needs 4B).
typedef float f32x4u __attribute__((ext_vector_type(4), aligned(4)));

// ws layout: [ lossSlot NBLK f32 ] — every block writes its slot, no init.

// K1: 512-thr block owns 32 vocab rows; wave owns 4.
//   A: preload ALL 4 owned cache rows into regs (8 dwordx4 in flight) THEN
//      scan gold (int4) + p-gather into LDS — read stream fully issued
//      before the barrier, decoupled from compute/stores.
//   B: per row (static unroll): blend/copy from regs + x walks, store.
// No __threadfence (R8: 302us), no single-address atomics (R11: +73us),
// no nontemporal (R7: 9.6x).
__global__ void __launch_bounds__(512, 3)
fused_row_kernel(const float* __restrict__ x, const float* __restrict__ p,
                 const int* __restrict__ gold, const int* __restrict__ mask,
                 const float* __restrict__ cache, float* __restrict__ out,
                 float* __restrict__ lossSlot) {
    __shared__ int lcnt[RPB];
    __shared__ int ltok[RPB][MAXTOK];
    __shared__ float lpw[RPB][MAXTOK];
    __shared__ float lossW[8];

    int tid = threadIdx.x;
    int base = blockIdx.x * RPB;
    if (tid < RPB) lcnt[tid] = 0;
    __syncthreads();

    int w = tid >> 6;
    int lane = tid & 63;
    int row0 = base + w * 4;  // wave w owns rows row0..row0+3
    int b = lane * 4;

    // Preload all 4 owned cache rows (issued before any scan dependency).
    float4 ca[4], cb[4];
    #pragma unroll
    for (int rr = 0; rr < 4; ++rr) {
        const float4* cr = (const float4*)cache + (size_t)(row0 + rr) * (DD / 4);
        ca[rr] = cr[lane];
        cb[rr] = cr[64 + lane];
    }

    // Phase A: scan gold as int4 (4 iters of 512 threads).
    const int4* g4 = (const int4*)gold;
    #pragma unroll
    for (int k = 0; k < NTOK / 2048; ++k) {
        int idx = tid + k * 512;
        int4 gg = g4[idx];
        int gi[4] = {gg.x, gg.y, gg.z, gg.w};
        #pragma unroll
        for (int c = 0; c < 4; ++c) {
            unsigned r = (unsigned)(gi[c] - base);
            if (r < (unsigned)RPB) {
                int i = idx * 4 + c;
                int slot = atomicAdd(&lcnt[r], 1);  // LDS atomic
                if (slot < MAXTOK) {
                    ltok[r][slot] = i;
                    float pg = p[(size_t)i * VD + gi[c]];
                    lpw[r][slot] = mask[i] ? -1.f : pg;  // sign marks pad
                }
            }
        }
    }
    __syncthreads();

    // Phase B: 4 rows per wave, all cache data already in regs.
    float lossAcc = 0.f;
    #pragma unroll
    for (int rr = 0; rr < 4; ++rr) {
        int row = row0 + rr;
        float* o = out + 1 + (size_t)row * DD;
        int rb = w * 4 + rr;
        int cnt = lcnt[rb];

        float4 va, vb;
        if (cnt == 0) {  // untouched row: passthrough
            va = ca[rr]; vb = cb[rr];
        } else {
            float sc = ca[rr].x * ca[rr].x + ca[rr].y * ca[rr].y
                     + ca[rr].z * ca[rr].z + ca[rr].w * ca[rr].w
                     + cb[rr].x * cb[rr].x + cb[rr].y * cb[rr].y
                     + cb[rr].z * cb[rr].z + cb[rr].w * cb[rr].w;
            #pragma unroll
            for (int off = 32; off; off >>= 1) sc += __shfl_xor(sc, off, 64);
            float rnc = 1.0f / fmaxf(sqrtf(sc), EPS_L2);

            float4 aa = {0.f, 0.f, 0.f, 0.f}, ab = {0.f, 0.f, 0.f, 0.f};
            int kend = cnt < MAXTOK ? cnt : MAXTOK;
            for (int k = 0; k < kend; ++k) {
                int t = ltok[rb][k];
                float pw = lpw[rb][k];  // < 0 means padded
                const float4* xr = (const float4*)x + (size_t)t * (DD / 4);
                float4 xa = xr[lane], xb = xr[64 + lane];

                float dot = xa.x * ca[rr].x + xa.y * ca[rr].y
                          + xa.z * ca[rr].z + xa.w * ca[rr].w
                          + xb.x * cb[rr].x + xb.y * cb[rr].y
                          + xb.z * cb[rr].z + xb.w * cb[rr].w;
                float sx = xa.x * xa.x + xa.y * xa.y + xa.z * xa.z + xa.w * xa.w
                         + xb.x * xb.x + xb.y * xb.y + xb.z * xb.z + xb.w * xb.w;
                #pragma unroll
                for (int off = 32; off; off >>= 1) {
                    dot += __shfl_xor(dot, off, 64);
                    sx += __shfl_xor(sx, off, 64);
                }
                if (pw >= 0.f) {
                    float rnx = 1.0f / fmaxf(sqrtf(sx), EPS_L2);
                    lossAcc += 2.f - 2.f * dot * rnx * rnc;
                    aa.x += pw * xa.x; aa.y += pw * xa.y;
                    aa.z += pw * xa.z; aa.w += pw * xa.w;
                    ab.x += pw * xb.x; ab.y += pw * xb.y;
                    ab.z += pw * xb.z; ab.w += pw * xb.w;
                }
            }
            float m = 0.1f / (float)cnt;  // counts include padded (ref)
            va.x = 0.9f * ca[rr].x + m * aa.x; va.y = 0.9f * ca[rr].y + m * aa.y;
            va.z = 0.9f * ca[rr].z + m * aa.z; va.w = 0.9f * ca[rr].w + m * aa.w;
            vb.x = 0.9f * cb[rr].x + m * ab.x; vb.y = 0.9f * cb[rr].y + m * ab.y;
            vb.z = 0.9f * cb[rr].z + m * ab.z; vb.w = 0.9f * cb[rr].w + m * ab.w;
        }
        f32x4u sva = {va.x, va.y, va.z, va.w};
        f32x4u svb = {vb.x, vb.y, vb.z, vb.w};
        *(f32x4u*)(o + b) = sva;
        *(f32x4u*)(o + 256 + b) = svb;
    }

    // Per-block loss (lossAcc wave-uniform after shfl reduces).
    if (lane == 0) lossW[w] = lossAcc;
    __syncthreads();
    if (tid == 0) {
        float s = 0.f;
        #pragma unroll
        for (int j = 0; j < 8; ++j) s += lossW[j];
        lossSlot[blockIdx.x] = s;  // plain store, every block writes
    }
}

// K2: reduce NBLK loss partials -> out[0].
__global__ void __launch_bounds__(256)
loss_reduce_kernel(const float* __restrict__ lossSlot, float* __restrict__ out) {
    __shared__ float sm[4];
    float a = 0.f;
    for (int i = threadIdx.x; i < NBLK; i += 256) a += lossSlot[i];
    #pragma unroll
    for (int off = 32; off; off >>= 1) a += __shfl_xor(a, off, 64);
    if ((threadIdx.x & 63) == 0) sm[threadIdx.x >> 6] = a;
    __syncthreads();
    if (threadIdx.x == 0) out[0] = sm[0] + sm[1] + sm[2] + sm[3];
}

extern "C" void kernel_launch(void* const* d_in, const int* in_sizes, int n_in,
                              void* d_out, int out_size, void* d_ws, size_t ws_size,
                              hipStream_t stream) {
    const float* x = (const float*)d_in[0];
    const float* p = (const float*)d_in[1];
    const int* gold = (const int*)d_in[2];
    const int* mask = (const int*)d_in[3];
    const float* cache = (const float*)d_in[4];
    float* out = (float*)d_out;
    float* lossSlot = (float*)d_ws;

    fused_row_kernel<<<NBLK, 512, 0, stream>>>(x, p, gold, mask, cache, out,
                                               lossSlot);
    loss_reduce_kernel<<<1, 256, 0, stream>>>(lossSlot, out);
}

// Round 18
// 34.038 us; speedup vs baseline: 1.0102x; 1.0102x over previous
//
#include <hip/hip_runtime.h>
#include <hip/hip_bf16.h>

#define BD 4
#define SD 2048
#define DD 512
#define VD 32000
#define NTOK (BD * SD)
#define EPS_L2 1e-12f
#define RPB 32                 // rows per block (8 waves x 4 rows each)
#define NBLK (VD / RPB)        // 1000
#define MAXTOK 32

// 16B vector with 4B alignment (stores land at out+1+...; dwordx4 needs 4B).
typedef float f32x4u __attribute__((ext_vector_type(4), aligned(4)));

// ws layout: [ lossSlot NBLK f32 ] — every block writes its slot, no init.

// K1: 512-thr block owns 32 vocab rows; wave owns 4.
//   A: preload ALL 4 owned cache rows into regs, then scan gold (int4) +
//      p-gather into LDS.
//   B: per row (static unroll): blend/copy from regs + x walks; output via
//      16B NON-TEMPORAL stores (no L2 write-allocate — the 64MB out stream
//      was thrashing the 32MB aggregate L2 against the read streams).
//      R7's nt disaster used SCALAR nt stores + nt loads; 16B nt stores
//      alone are the isolated test.
// No __threadfence (R8: 302us), no single-address atomics (R11: +73us).
__global__ void __launch_bounds__(512, 3)
fused_row_kernel(const float* __restrict__ x, const float* __restrict__ p,
                 const int* __restrict__ gold, const int* __restrict__ mask,
                 const float* __restrict__ cache, float* __restrict__ out,
                 float* __restrict__ lossSlot) {
    __shared__ int lcnt[RPB];
    __shared__ int ltok[RPB][MAXTOK];
    __shared__ float lpw[RPB][MAXTOK];
    __shared__ float lossW[8];

    int tid = threadIdx.x;
    int base = blockIdx.x * RPB;
    if (tid < RPB) lcnt[tid] = 0;
    __syncthreads();

    int w = tid >> 6;
    int lane = tid & 63;
    int row0 = base + w * 4;  // wave w owns rows row0..row0+3
    int b = lane * 4;

    // Preload all 4 owned cache rows (issued before any scan dependency).
    float4 ca[4], cb[4];
    #pragma unroll
    for (int rr = 0; rr < 4; ++rr) {
        const float4* cr = (const float4*)cache + (size_t)(row0 + rr) * (DD / 4);
        ca[rr] = cr[lane];
        cb[rr] = cr[64 + lane];
    }

    // Phase A: scan gold as int4 (4 iters of 512 threads).
    const int4* g4 = (const int4*)gold;
    #pragma unroll
    for (int k = 0; k < NTOK / 2048; ++k) {
        int idx = tid + k * 512;
        int4 gg = g4[idx];
        int gi[4] = {gg.x, gg.y, gg.z, gg.w};
        #pragma unroll
        for (int c = 0; c < 4; ++c) {
            unsigned r = (unsigned)(gi[c] - base);
            if (r < (unsigned)RPB) {
                int i = idx * 4 + c;
                int slot = atomicAdd(&lcnt[r], 1);  // LDS atomic
                if (slot < MAXTOK) {
                    ltok[r][slot] = i;
                    float pg = p[(size_t)i * VD + gi[c]];
                    lpw[r][slot] = mask[i] ? -1.f : pg;  // sign marks pad
                }
            }
        }
    }
    __syncthreads();

    // Phase B: 4 rows per wave, all cache data already in regs.
    float lossAcc = 0.f;
    #pragma unroll
    for (int rr = 0; rr < 4; ++rr) {
        int row = row0 + rr;
        float* o = out + 1 + (size_t)row * DD;
        int rb = w * 4 + rr;
        int cnt = lcnt[rb];

        float4 va, vb;
        if (cnt == 0) {  // untouched row: passthrough
            va = ca[rr]; vb = cb[rr];
        } else {
            float sc = ca[rr].x * ca[rr].x + ca[rr].y * ca[rr].y
                     + ca[rr].z * ca[rr].z + ca[rr].w * ca[rr].w
                     + cb[rr].x * cb[rr].x + cb[rr].y * cb[rr].y
                     + cb[rr].z * cb[rr].z + cb[rr].w * cb[rr].w;
            #pragma unroll
            for (int off = 32; off; off >>= 1) sc += __shfl_xor(sc, off, 64);
            float rnc = 1.0f / fmaxf(sqrtf(sc), EPS_L2);

            float4 aa = {0.f, 0.f, 0.f, 0.f}, ab = {0.f, 0.f, 0.f, 0.f};
            int kend = cnt < MAXTOK ? cnt : MAXTOK;
            for (int k = 0; k < kend; ++k) {
                int t = ltok[rb][k];
                float pw = lpw[rb][k];  // < 0 means padded
                const float4* xr = (const float4*)x + (size_t)t * (DD / 4);
                float4 xa = xr[lane], xb = xr[64 + lane];

                float dot = xa.x * ca[rr].x + xa.y * ca[rr].y
                          + xa.z * ca[rr].z + xa.w * ca[rr].w
                          + xb.x * cb[rr].x + xb.y * cb[rr].y
                          + xb.z * cb[rr].z + xb.w * cb[rr].w;
                float sx = xa.x * xa.x + xa.y * xa.y + xa.z * xa.z + xa.w * xa.w
                         + xb.x * xb.x + xb.y * xb.y + xb.z * xb.z + xb.w * xb.w;
                #pragma unroll
                for (int off = 32; off; off >>= 1) {
                    dot += __shfl_xor(dot, off, 64);
                    sx += __shfl_xor(sx, off, 64);
                }
                if (pw >= 0.f) {
                    float rnx = 1.0f / fmaxf(sqrtf(sx), EPS_L2);
                    lossAcc += 2.f - 2.f * dot * rnx * rnc;
                    aa.x += pw * xa.x; aa.y += pw * xa.y;
                    aa.z += pw * xa.z; aa.w += pw * xa.w;
                    ab.x += pw * xb.x; ab.y += pw * xb.y;
                    ab.z += pw * xb.z; ab.w += pw * xb.w;
                }
            }
            float m = 0.1f / (float)cnt;  // counts include padded (ref)
            va.x = 0.9f * ca[rr].x + m * aa.x; va.y = 0.9f * ca[rr].y + m * aa.y;
            va.z = 0.9f * ca[rr].z + m * aa.z; va.w = 0.9f * ca[rr].w + m * aa.w;
            vb.x = 0.9f * cb[rr].x + m * ab.x; vb.y = 0.9f * cb[rr].y + m * ab.y;
            vb.z = 0.9f * cb[rr].z + m * ab.z; vb.w = 0.9f * cb[rr].w + m * ab.w;
        }
        f32x4u sva = {va.x, va.y, va.z, va.w};
        f32x4u svb = {vb.x, vb.y, vb.z, vb.w};
        __builtin_nontemporal_store(sva, (f32x4u*)(o + b));
        __builtin_nontemporal_store(svb, (f32x4u*)(o + 256 + b));
    }

    // Per-block loss (lossAcc wave-uniform after shfl reduces).
    if (lane == 0) lossW[w] = lossAcc;
    __syncthreads();
    if (tid == 0) {
        float s = 0.f;
        #pragma unroll
        for (int j = 0; j < 8; ++j) s += lossW[j];
        lossSlot[blockIdx.x] = s;  // plain store, every block writes
    }
}

// K2: reduce NBLK loss partials -> out[0].
__global__ void __launch_bounds__(256)
loss_reduce_kernel(const float* __restrict__ lossSlot, float* __restrict__ out) {
    __shared__ float sm[4];
    float a = 0.f;
    for (int i = threadIdx.x; i < NBLK; i += 256) a += lossSlot[i];
    #pragma unroll
    for (int off = 32; off; off >>= 1) a += __shfl_xor(a, off, 64);
    if ((threadIdx.x & 63) == 0) sm[threadIdx.x >> 6] = a;
    __syncthreads();
    if (threadIdx.x == 0) out[0] = sm[0] + sm[1] + sm[2] + sm[3];
}

extern "C" void kernel_launch(void* const* d_in, const int* in_sizes, int n_in,
                              void* d_out, int out_size, void* d_ws, size_t ws_size,
                              hipStream_t stream) {
    const float* x = (const float*)d_in[0];
    const float* p = (const float*)d_in[1];
    const int* gold = (const int*)d_in[2];
    const int* mask = (const int*)d_in[3];
    const float* cache = (const float*)d_in[4];
    float* out = (float*)d_out;
    float* lossSlot = (float*)d_ws;

    fused_row_kernel<<<NBLK, 512, 0, stream>>>(x, p, gold, mask, cache, out,
                                               lossSlot);
    loss_reduce_kernel<<<1, 256, 0, stream>>>(lossSlot, out);
}